// Round 1
// baseline (264.642 us; speedup 1.0000x reference)
//
#include <hip/hip_runtime.h>
#include <math.h>

#define NCLASS 1000
#define NCHUNK 250            // 1000 / 4 float4 chunks per row
#define ROWS_PER_WAVE 4
#define WAVES_PER_BLOCK 4
#define ROWS_PER_BLOCK (ROWS_PER_WAVE * WAVES_PER_BLOCK)

// Single fused kernel: (a) max over a slice of distance_matrix, (b) 16 rows
// of fused max/argmax + logsumexp + gather, partials to ws, then the LAST
// block to finish (atomic counter) reduces the partials and writes out.
// Counter at ws[2*nb] is zeroed by a hipMemsetAsync before launch.
__global__ __launch_bounds__(256) void hce_fused(
    const float* __restrict__ y_pred,
    const int*   __restrict__ y_true,
    const float* __restrict__ D,
    float* __restrict__ partial,   // [0,nb): sums; [nb,2nb): D maxes; [2nb]: counter
    float* __restrict__ out,
    int nb, int dsize, float invB)
{
    const int tid  = threadIdx.x;
    const int lane = tid & 63;
    const int wave = tid >> 6;
    const int b    = blockIdx.x;

    // ---- part 1: distance_matrix max over this block's slice ----
    float dm = -1.0f;                      // D is uniform[0,1): nonnegative
    for (int i = b * 256 + tid; i < dsize; i += nb * 256)
        dm = fmaxf(dm, D[i]);
    #pragma unroll
    for (int off = 32; off; off >>= 1)
        dm = fmaxf(dm, __shfl_xor(dm, off, 64));

    __shared__ float smax[WAVES_PER_BLOCK];
    __shared__ float ssum[WAVES_PER_BLOCK];
    __shared__ int   sdone;
    if (lane == 0) smax[wave] = dm;

    // ---- part 2: 4 rows per wave ----
    float acc = 0.0f;
    const int row0 = b * ROWS_PER_BLOCK + wave * ROWS_PER_WAVE;
    for (int r = 0; r < ROWS_PER_WAVE; ++r) {
        const int row = row0 + r;
        const float4* rp4 = (const float4*)(y_pred + (size_t)row * NCLASS);

        float4 v[4];
        #pragma unroll
        for (int t = 0; t < 4; ++t) {
            int c = lane + 64 * t;
            if (c < NCHUNK) v[t] = rp4[c];
        }
        const int nt = (lane + 192 < NCHUNK) ? 4 : 3;

        // phase 1: max + argmax (first occurrence == min col among ties)
        float m = -INFINITY; int arg = 0;
        #pragma unroll
        for (int t = 0; t < 4; ++t) {
            if (t < nt) {
                int col = 4 * (lane + 64 * t);
                if (v[t].x > m) { m = v[t].x; arg = col;     }
                if (v[t].y > m) { m = v[t].y; arg = col + 1; }
                if (v[t].z > m) { m = v[t].z; arg = col + 2; }
                if (v[t].w > m) { m = v[t].w; arg = col + 3; }
            }
        }
        #pragma unroll
        for (int off = 32; off; off >>= 1) {
            float om = __shfl_xor(m,   off, 64);
            int   oa = __shfl_xor(arg, off, 64);
            if (om > m || (om == m && oa < arg)) { m = om; arg = oa; }
        }

        // phase 2: sum of exp(x - m)
        float s = 0.0f;
        #pragma unroll
        for (int t = 0; t < 4; ++t) {
            if (t < nt) {
                s += __expf(v[t].x - m) + __expf(v[t].y - m)
                   + __expf(v[t].z - m) + __expf(v[t].w - m);
            }
        }
        #pragma unroll
        for (int off = 32; off; off >>= 1)
            s += __shfl_xor(s, off, 64);

        if (lane == 0) {
            int   tgt  = y_true[row];
            float xt   = y_pred[(size_t)row * NCLASS + tgt];
            float logp = xt - m - __logf(s);
            float d    = D[arg * NCLASS + tgt];
            acc += logp * d;
        }
    }

    if (lane == 0) ssum[wave] = acc;
    __syncthreads();
    if (tid == 0) {
        partial[b]      = ssum[0] + ssum[1] + ssum[2] + ssum[3];
        partial[nb + b] = fmaxf(fmaxf(smax[0], smax[1]),
                                fmaxf(smax[2], smax[3]));
        __threadfence();   // release: partials visible device-wide before counter bump
        unsigned prev = atomicAdd((unsigned int*)(partial + 2 * (size_t)nb), 1u);
        sdone = (prev == (unsigned)(nb - 1));
    }
    __syncthreads();
    if (!sdone) return;

    // ---- last block: finalize (identical reduction order to old hce_finalize) ----
    __threadfence();       // acquire: invalidate local caches before reading partials
    float s = 0.0f, mx = -1.0f;
    for (int i = tid; i < nb; i += 256) {
        s  += partial[i];
        mx  = fmaxf(mx, partial[nb + i]);
    }
    #pragma unroll
    for (int off = 32; off; off >>= 1) {
        s  += __shfl_xor(s, off, 64);
        mx  = fmaxf(mx, __shfl_xor(mx, off, 64));
    }
    if (lane == 0) { ssum[wave] = s; smax[wave] = mx; }
    __syncthreads();
    if (tid == 0) {
        float S = ssum[0] + ssum[1] + ssum[2] + ssum[3];
        float M = fmaxf(fmaxf(smax[0], smax[1]), fmaxf(smax[2], smax[3]));
        out[0] = -S * invB / M;
    }
}

extern "C" void kernel_launch(void* const* d_in, const int* in_sizes, int n_in,
                              void* d_out, int out_size, void* d_ws, size_t ws_size,
                              hipStream_t stream) {
    const float* y_pred = (const float*)d_in[0];
    const int*   y_true = (const int*)  d_in[1];
    const float* D      = (const float*)d_in[2];
    // d_in[3] (fix_layer) is dead code in the reference.
    float* out = (float*)d_out;
    float* ws  = (float*)d_ws;

    const int B     = in_sizes[1];          // 32768
    const int dsize = in_sizes[2];          // 1000*1000
    const int nb    = B / ROWS_PER_BLOCK;   // 2048 blocks

    // zero the completion counter (workspace is poisoned every iteration)
    hipMemsetAsync(ws + 2 * (size_t)nb, 0, sizeof(unsigned int), stream);
    hce_fused<<<nb, 256, 0, stream>>>(y_pred, y_true, D, ws, out,
                                      nb, dsize, 1.0f / (float)B);
}

// Round 2
// 201.603 us; speedup vs baseline: 1.3127x; 1.3127x over previous
//
#include <hip/hip_runtime.h>
#include <math.h>

#define NCLASS 1000
#define NCHUNK 250            // 1000 / 4 float4 chunks per row
#define ROWS_PER_WAVE 4
#define WAVES_PER_BLOCK 4
#define ROWS_PER_BLOCK (ROWS_PER_WAVE * WAVES_PER_BLOCK)

// Two-kernel structure (fused last-block version regressed -64us: device-scope
// threadfence + 2048 same-address atomics serialize across non-coherent XCD L2s;
// the kernel-boundary release is far cheaper).
//
// Main kernel restructured for memory-level parallelism: all row loads + target
// gathers issued upfront (16KB in flight per wave), the 4 rows' shuffle
// butterflies interleaved so DS latency overlaps, and the dependent
// D[arg,tgt] gathers done lane-parallel (lanes 0..3) instead of serially
// by lane 0.
__global__ __launch_bounds__(256, 4) void hce_main(
    const float* __restrict__ y_pred,
    const int*   __restrict__ y_true,
    const float* __restrict__ D,
    float* __restrict__ partial,   // [0,nb): sums; [nb,2nb): D-slice maxes
    int nb, int dsize)
{
    const int tid  = threadIdx.x;
    const int lane = tid & 63;
    const int wave = tid >> 6;
    const int b    = blockIdx.x;
    const int row0 = b * ROWS_PER_BLOCK + wave * ROWS_PER_WAVE;

    // ---- issue ALL independent global loads upfront (MLP) ----
    // (a) this wave's 4 targets, lane-parallel
    int tgt = 0;
    if (lane < ROWS_PER_WAVE) tgt = y_true[row0 + lane];

    // (b) 4 rows x 4 float4 chunks = 16 outstanding dwordx4 per lane
    float4 v[ROWS_PER_WAVE][4];
    #pragma unroll
    for (int r = 0; r < ROWS_PER_WAVE; ++r) {
        const float4* rp4 = (const float4*)(y_pred + (size_t)(row0 + r) * NCLASS);
        #pragma unroll
        for (int t = 0; t < 4; ++t) {
            int c = lane + 64 * t;
            if (c < NCHUNK) v[r][t] = rp4[c];
        }
    }

    // (c) distance_matrix max over this block's slice (independent loads)
    float dm = -1.0f;                      // D is uniform[0,1): nonnegative
    for (int i = b * 256 + tid; i < dsize; i += nb * 256)
        dm = fmaxf(dm, D[i]);

    // (d) target logit gather (depends only on tgt), lane-parallel
    float xt = 0.0f;
    if (lane < ROWS_PER_WAVE) xt = y_pred[(size_t)(row0 + lane) * NCLASS + tgt];

    // ---- D-max butterfly ----
    #pragma unroll
    for (int off = 32; off; off >>= 1)
        dm = fmaxf(dm, __shfl_xor(dm, off, 64));

    __shared__ float smax[WAVES_PER_BLOCK];
    __shared__ float ssum[WAVES_PER_BLOCK];
    if (lane == 0) smax[wave] = dm;

    const int nt = (lane + 192 < NCHUNK) ? 4 : 3;

    // ---- phase 1: max + argmax for all 4 rows (butterflies interleaved) ----
    float m[ROWS_PER_WAVE]; int arg[ROWS_PER_WAVE];
    #pragma unroll
    for (int r = 0; r < ROWS_PER_WAVE; ++r) {
        m[r] = -INFINITY; arg[r] = 0;
        #pragma unroll
        for (int t = 0; t < 4; ++t) {
            if (t < nt) {
                int col = 4 * (lane + 64 * t);
                if (v[r][t].x > m[r]) { m[r] = v[r][t].x; arg[r] = col;     }
                if (v[r][t].y > m[r]) { m[r] = v[r][t].y; arg[r] = col + 1; }
                if (v[r][t].z > m[r]) { m[r] = v[r][t].z; arg[r] = col + 2; }
                if (v[r][t].w > m[r]) { m[r] = v[r][t].w; arg[r] = col + 3; }
            }
        }
    }
    #pragma unroll
    for (int off = 32; off; off >>= 1) {
        #pragma unroll
        for (int r = 0; r < ROWS_PER_WAVE; ++r) {
            float om = __shfl_xor(m[r],   off, 64);
            int   oa = __shfl_xor(arg[r], off, 64);
            if (om > m[r] || (om == m[r] && oa < arg[r])) { m[r] = om; arg[r] = oa; }
        }
    }

    // ---- phase 2: sum of exp(x - m) for all 4 rows ----
    float s[ROWS_PER_WAVE];
    #pragma unroll
    for (int r = 0; r < ROWS_PER_WAVE; ++r) {
        s[r] = 0.0f;
        #pragma unroll
        for (int t = 0; t < 4; ++t) {
            if (t < nt) {
                s[r] += __expf(v[r][t].x - m[r]) + __expf(v[r][t].y - m[r])
                      + __expf(v[r][t].z - m[r]) + __expf(v[r][t].w - m[r]);
            }
        }
    }
    #pragma unroll
    for (int off = 32; off; off >>= 1) {
        #pragma unroll
        for (int r = 0; r < ROWS_PER_WAVE; ++r)
            s[r] += __shfl_xor(s[r], off, 64);
    }

    // ---- tail: lane r (r<4) finishes row r; D-gathers go out in parallel ----
    // select row-r state on lane r via cndmask chain (compile-time indices only)
    float mr = m[0], sr = s[0]; int ar = arg[0];
    if (lane == 1) { mr = m[1]; sr = s[1]; ar = arg[1]; }
    if (lane == 2) { mr = m[2]; sr = s[2]; ar = arg[2]; }
    if (lane == 3) { mr = m[3]; sr = s[3]; ar = arg[3]; }

    float contrib = 0.0f;
    if (lane < ROWS_PER_WAVE) {
        float d = D[(size_t)ar * NCLASS + tgt];
        contrib = (xt - mr - __logf(sr)) * d;
    }

    // reconstruct the exact left-associative per-row accumulation order
    float c0 = __shfl(contrib, 0, 64);
    float c1 = __shfl(contrib, 1, 64);
    float c2 = __shfl(contrib, 2, 64);
    float c3 = __shfl(contrib, 3, 64);
    float acc = ((c0 + c1) + c2) + c3;

    if (lane == 0) ssum[wave] = acc;
    __syncthreads();
    if (tid == 0) {
        partial[b]      = ssum[0] + ssum[1] + ssum[2] + ssum[3];
        partial[nb + b] = fmaxf(fmaxf(smax[0], smax[1]),
                                fmaxf(smax[2], smax[3]));
    }
}

__global__ __launch_bounds__(256) void hce_finalize(
    const float* __restrict__ partial, int nb,
    float* __restrict__ out, float invB)
{
    const int tid  = threadIdx.x;
    const int lane = tid & 63;
    const int wave = tid >> 6;
    float s = 0.0f, mx = -1.0f;
    for (int i = tid; i < nb; i += 256) {
        s  += partial[i];
        mx  = fmaxf(mx, partial[nb + i]);
    }
    #pragma unroll
    for (int off = 32; off; off >>= 1) {
        s  += __shfl_xor(s, off, 64);
        mx  = fmaxf(mx, __shfl_xor(mx, off, 64));
    }
    __shared__ float ss[4], sm[4];
    if (lane == 0) { ss[wave] = s; sm[wave] = mx; }
    __syncthreads();
    if (tid == 0) {
        float S = ss[0] + ss[1] + ss[2] + ss[3];
        float M = fmaxf(fmaxf(sm[0], sm[1]), fmaxf(sm[2], sm[3]));
        out[0] = -S * invB / M;
    }
}

extern "C" void kernel_launch(void* const* d_in, const int* in_sizes, int n_in,
                              void* d_out, int out_size, void* d_ws, size_t ws_size,
                              hipStream_t stream) {
    const float* y_pred = (const float*)d_in[0];
    const int*   y_true = (const int*)  d_in[1];
    const float* D      = (const float*)d_in[2];
    // d_in[3] (fix_layer) is dead code in the reference.
    float* out = (float*)d_out;
    float* ws  = (float*)d_ws;

    const int B     = in_sizes[1];          // 32768
    const int dsize = in_sizes[2];          // 1000*1000
    const int nb    = B / ROWS_PER_BLOCK;   // 2048 blocks

    hce_main<<<nb, 256, 0, stream>>>(y_pred, y_true, D, ws, nb, dsize);
    hce_finalize<<<1, 256, 0, stream>>>(ws, nb, out, 1.0f / (float)B);
}

// Round 3
// 195.618 us; speedup vs baseline: 1.3529x; 1.0306x over previous
//
#include <hip/hip_runtime.h>
#include <math.h>

#define NCLASS 1000
#define NCHUNK 250            // 1000 / 4 float4 chunks per row
#define WAVES_PER_BLOCK 16
#define ROWS_PER_BLOCK 16     // ONE row per wave
#define BLOCK 1024

// Round-3 structure: TLP over ILP. Round 2's 4-rows/wave ILP restructure was
// exactly neutral (compiler sinks prefetched loads; 16 waves/CU can't hide the
// per-wave serial chain). Now: 1 row/wave, ~45 VGPRs -> 8 waves/SIMD
// (32 waves/CU, 2x round 0), per-wave serial chain 4x shorter.
// 1024-thread blocks keep 16 rows/block so thread 0 can recombine the 16
// per-wave terms in EXACTLY round 0's association order -> bit-identical
// result (absmax 0.0), nb=2048 and finalize unchanged.
__global__ __launch_bounds__(1024, 8) void hce_main(
    const float* __restrict__ y_pred,
    const int*   __restrict__ y_true,
    const float* __restrict__ D,
    float* __restrict__ partial,   // [0,nb): sums; [nb,2nb): D-slice maxes
    int nb, int dsize)
{
    const int tid  = threadIdx.x;
    const int lane = tid & 63;
    const int wave = tid >> 6;
    const int b    = blockIdx.x;
    const int row  = b * ROWS_PER_BLOCK + wave;

    // independent early loads: target index, then target logit right behind it
    int tgt = 0;
    if (lane == 0) tgt = y_true[row];

    const float4* rp4 = (const float4*)(y_pred + (size_t)row * NCLASS);
    float4 v[4];
    #pragma unroll
    for (int t = 0; t < 4; ++t) {
        int c = lane + 64 * t;
        if (c < NCHUNK) v[t] = rp4[c];
    }

    float xt = 0.0f;
    if (lane == 0) xt = y_pred[(size_t)row * NCLASS + tgt];

    // ---- distance_matrix max over this block's slice ----
    // stride nb*BLOCK = 2M > dsize: each thread loads at most one element;
    // union over blocks covers [0,dsize). Max is order-free -> exact.
    float dm = -1.0f;                      // D is uniform[0,1): nonnegative
    for (int i = b * BLOCK + tid; i < dsize; i += nb * BLOCK)
        dm = fmaxf(dm, D[i]);
    #pragma unroll
    for (int off = 32; off; off >>= 1)
        dm = fmaxf(dm, __shfl_xor(dm, off, 64));

    __shared__ float smax[WAVES_PER_BLOCK];
    __shared__ float ssum[WAVES_PER_BLOCK];
    if (lane == 0) smax[wave] = dm;

    const int nt = (lane + 192 < NCHUNK) ? 4 : 3;

    // ---- phase 1: max + argmax (first occurrence == min col among ties) ----
    float m = -INFINITY; int arg = 0;
    #pragma unroll
    for (int t = 0; t < 4; ++t) {
        if (t < nt) {
            int col = 4 * (lane + 64 * t);
            if (v[t].x > m) { m = v[t].x; arg = col;     }
            if (v[t].y > m) { m = v[t].y; arg = col + 1; }
            if (v[t].z > m) { m = v[t].z; arg = col + 2; }
            if (v[t].w > m) { m = v[t].w; arg = col + 3; }
        }
    }
    #pragma unroll
    for (int off = 32; off; off >>= 1) {
        float om = __shfl_xor(m,   off, 64);
        int   oa = __shfl_xor(arg, off, 64);
        if (om > m || (om == m && oa < arg)) { m = om; arg = oa; }
    }

    // ---- phase 2: sum of exp(x - m) ----
    float s = 0.0f;
    #pragma unroll
    for (int t = 0; t < 4; ++t) {
        if (t < nt) {
            s += __expf(v[t].x - m) + __expf(v[t].y - m)
               + __expf(v[t].z - m) + __expf(v[t].w - m);
        }
    }
    #pragma unroll
    for (int off = 32; off; off >>= 1)
        s += __shfl_xor(s, off, 64);

    // ---- tail: one gather per wave ----
    if (lane == 0) {
        float logp = xt - m - __logf(s);
        float d    = D[(size_t)arg * NCLASS + tgt];
        ssum[wave] = logp * d;
    }
    __syncthreads();

    if (tid == 0) {
        // EXACT round-0 association: old ssum[w] = ((c0+c1)+c2)+c3 over its
        // 4 rows; old partial = ((ssum0+ssum1)+ssum2)+ssum3.
        float a0 = ((ssum[0]  + ssum[1])  + ssum[2])  + ssum[3];
        float a1 = ((ssum[4]  + ssum[5])  + ssum[6])  + ssum[7];
        float a2 = ((ssum[8]  + ssum[9])  + ssum[10]) + ssum[11];
        float a3 = ((ssum[12] + ssum[13]) + ssum[14]) + ssum[15];
        partial[b] = ((a0 + a1) + a2) + a3;

        float m01 = fmaxf(fmaxf(smax[0],  smax[1]),  fmaxf(smax[2],  smax[3]));
        float m23 = fmaxf(fmaxf(smax[4],  smax[5]),  fmaxf(smax[6],  smax[7]));
        float m45 = fmaxf(fmaxf(smax[8],  smax[9]),  fmaxf(smax[10], smax[11]));
        float m67 = fmaxf(fmaxf(smax[12], smax[13]), fmaxf(smax[14], smax[15]));
        partial[nb + b] = fmaxf(fmaxf(m01, m23), fmaxf(m45, m67));
    }
}

__global__ __launch_bounds__(256) void hce_finalize(
    const float* __restrict__ partial, int nb,
    float* __restrict__ out, float invB)
{
    const int tid  = threadIdx.x;
    const int lane = tid & 63;
    const int wave = tid >> 6;
    float s = 0.0f, mx = -1.0f;
    for (int i = tid; i < nb; i += 256) {
        s  += partial[i];
        mx  = fmaxf(mx, partial[nb + i]);
    }
    #pragma unroll
    for (int off = 32; off; off >>= 1) {
        s  += __shfl_xor(s, off, 64);
        mx  = fmaxf(mx, __shfl_xor(mx, off, 64));
    }
    __shared__ float ss[4], sm[4];
    if (lane == 0) { ss[wave] = s; sm[wave] = mx; }
    __syncthreads();
    if (tid == 0) {
        float S = ss[0] + ss[1] + ss[2] + ss[3];
        float M = fmaxf(fmaxf(sm[0], sm[1]), fmaxf(sm[2], sm[3]));
        out[0] = -S * invB / M;
    }
}

extern "C" void kernel_launch(void* const* d_in, const int* in_sizes, int n_in,
                              void* d_out, int out_size, void* d_ws, size_t ws_size,
                              hipStream_t stream) {
    const float* y_pred = (const float*)d_in[0];
    const int*   y_true = (const int*)  d_in[1];
    const float* D      = (const float*)d_in[2];
    // d_in[3] (fix_layer) is dead code in the reference.
    float* out = (float*)d_out;
    float* ws  = (float*)d_ws;

    const int B     = in_sizes[1];          // 32768
    const int dsize = in_sizes[2];          // 1000*1000
    const int nb    = B / ROWS_PER_BLOCK;   // 2048 blocks

    hce_main<<<nb, BLOCK, 0, stream>>>(y_pred, y_true, D, ws, nb, dsize);
    hce_finalize<<<1, 256, 0, stream>>>(ws, nb, out, 1.0f / (float)B);
}